// Round 1
// baseline (450.233 us; speedup 1.0000x reference)
//
#include <hip/hip_runtime.h>

// LIF layer: T=16, B=32, C=128, H=32, W=32
// v = v*0.5 + I[t]; spike = (v >= 1.0); v -= spike*1.0
// Input/output: float32, shape (T, B, C, H, W), T outermost.
// Pure streaming recurrence over T per neuron -> one thread owns 4 neurons
// (float4), v lives in registers, loop T internally. 512 MiB total traffic.

constexpr int T_STEPS = 16;
constexpr int N_NEUR  = 32 * 128 * 32 * 32;  // 4,194,304 neurons per step
constexpr int N4      = N_NEUR / 4;          // 1,048,576 float4 elements
constexpr float DECAY = 0.5f;
constexpr float THR   = 1.0f;

__global__ __launch_bounds__(256) void lif_fwd(const float4* __restrict__ x,
                                               float4* __restrict__ out) {
    const int i = blockIdx.x * 256 + threadIdx.x;  // float4 index in [0, N4)
    float vx = 0.0f, vy = 0.0f, vz = 0.0f, vw = 0.0f;
#pragma unroll
    for (int t = 0; t < T_STEPS; ++t) {
        const float4 c = x[t * N4 + i];
        vx = vx * DECAY + c.x;
        vy = vy * DECAY + c.y;
        vz = vz * DECAY + c.z;
        vw = vw * DECAY + c.w;
        const float sx = (vx >= THR) ? 1.0f : 0.0f;
        const float sy = (vy >= THR) ? 1.0f : 0.0f;
        const float sz = (vz >= THR) ? 1.0f : 0.0f;
        const float sw = (vw >= THR) ? 1.0f : 0.0f;
        vx -= sx * THR;
        vy -= sy * THR;
        vz -= sz * THR;
        vw -= sw * THR;
        out[t * N4 + i] = make_float4(sx, sy, sz, sw);
    }
}

extern "C" void kernel_launch(void* const* d_in, const int* in_sizes, int n_in,
                              void* d_out, int out_size, void* d_ws, size_t ws_size,
                              hipStream_t stream) {
    const float4* x = (const float4*)d_in[0];
    float4* out = (float4*)d_out;
    // Exact grid: 1,048,576 float4 / 256 threads = 4096 blocks.
    lif_fwd<<<dim3(N4 / 256), dim3(256), 0, stream>>>(x, out);
}

// Round 2
// 437.025 us; speedup vs baseline: 1.0302x; 1.0302x over previous
//
#include <hip/hip_runtime.h>

// LIF layer: T=16, B=32, C=128, H=32, W=32, float32 in/out.
// v = v*0.5 + I[t]; spike = (v >= 1.0); v -= spike  (subtract reset)
//
// Round-1 lesson: single float4 stream/thread = latency-bound (VGPR=20,
// ~1 load in flight, 2.4 TB/s). Fix: G=4 independent float4 groups per
// thread + software pipeline over T (prefetch t+1 while computing t)
// => ~8 outstanding loads/thread. Nontemporal stores keep the write-once
// output from evicting input lines in L2/L3.

constexpr int T_STEPS  = 16;
constexpr int N_NEUR   = 32 * 128 * 32 * 32;   // 4,194,304 per time step
constexpr int N4       = N_NEUR / 4;           // 1,048,576 float4 / step
constexpr int G        = 4;                    // independent groups per thread
constexpr int NTHREADS = N4 / G;               // 262,144 threads
constexpr int BLK      = 256;
constexpr float DECAY  = 0.5f;
constexpr float THR    = 1.0f;

typedef float f32x4 __attribute__((ext_vector_type(4)));

__global__ __launch_bounds__(BLK) void lif_fwd(const float4* __restrict__ x,
                                               float4* __restrict__ out) {
    const int tid = blockIdx.x * BLK + threadIdx.x;   // [0, NTHREADS)

    float4 v[G];
#pragma unroll
    for (int g = 0; g < G; ++g) v[g] = make_float4(0.f, 0.f, 0.f, 0.f);

    float4 cur[G], nxt[G];
#pragma unroll
    for (int g = 0; g < G; ++g) cur[g] = x[tid + g * NTHREADS];

    for (int t = 0; t < T_STEPS; ++t) {
        // Prefetch t+1 (independent of the compute below -> overlaps latency)
        if (t + 1 < T_STEPS) {
            const size_t nbase = (size_t)(t + 1) * N4 + tid;
#pragma unroll
            for (int g = 0; g < G; ++g) nxt[g] = x[nbase + (size_t)g * NTHREADS];
        }

        const size_t obase = (size_t)t * N4 + tid;
#pragma unroll
        for (int g = 0; g < G; ++g) {
            float4 s;
            v[g].x = v[g].x * DECAY + cur[g].x;
            v[g].y = v[g].y * DECAY + cur[g].y;
            v[g].z = v[g].z * DECAY + cur[g].z;
            v[g].w = v[g].w * DECAY + cur[g].w;
            s.x = (v[g].x >= THR) ? 1.0f : 0.0f;
            s.y = (v[g].y >= THR) ? 1.0f : 0.0f;
            s.z = (v[g].z >= THR) ? 1.0f : 0.0f;
            s.w = (v[g].w >= THR) ? 1.0f : 0.0f;
            v[g].x -= s.x;
            v[g].y -= s.y;
            v[g].z -= s.z;
            v[g].w -= s.w;
            f32x4 sv = {s.x, s.y, s.z, s.w};
            __builtin_nontemporal_store(sv, (f32x4*)&out[obase + (size_t)g * NTHREADS]);
        }

#pragma unroll
        for (int g = 0; g < G; ++g) cur[g] = nxt[g];
    }
}

extern "C" void kernel_launch(void* const* d_in, const int* in_sizes, int n_in,
                              void* d_out, int out_size, void* d_ws, size_t ws_size,
                              hipStream_t stream) {
    const float4* x = (const float4*)d_in[0];
    float4* out = (float4*)d_out;
    lif_fwd<<<dim3(NTHREADS / BLK), dim3(BLK), 0, stream>>>(x, out);
}